// Round 1
// baseline (489.138 us; speedup 1.0000x reference)
//
#include <hip/hip_runtime.h>
#include <cstdint>
#include <cstddef>

#define N_NODES 4096
#define FEAT 128
#define KCH 4
#define NNZ_CAP (1 << 18)   // 262144 entries; expected nnz ~65.5K (mean + ~770 sd)

// ---- Pass 1: column sums of adj (deg[x] = sum_i adj[i,x]); binary adj => also nnz count
__global__ void k_deg(const float* __restrict__ adj, float* __restrict__ deg) {
    int gx = blockIdx.x * blockDim.x + threadIdx.x;   // 0..1023, owns 4 columns
    int i0 = blockIdx.y * 32;
    const float4* a4 = reinterpret_cast<const float4*>(adj);
    float s0 = 0.f, s1 = 0.f, s2 = 0.f, s3 = 0.f;
    for (int r = 0; r < 32; ++r) {
        float4 q = a4[(size_t)(i0 + r) * (N_NODES / 4) + gx];
        s0 += q.x; s1 += q.y; s2 += q.z; s3 += q.w;
    }
    int x = gx * 4;
    atomicAdd(&deg[x + 0], s0);
    atomicAdd(&deg[x + 1], s1);
    atomicAdd(&deg[x + 2], s2);
    atomicAdd(&deg[x + 3], s3);
}

// ---- Scan: dinv = rsqrt(max(deg,1)); exclusive prefix sum of counts -> rowptr, cursors
__global__ __launch_bounds__(1024) void k_scan(const float* __restrict__ deg,
                                               float* __restrict__ dinv,
                                               int* __restrict__ rowptr,
                                               int* __restrict__ cur) {
    __shared__ int part[1024];
    int t = threadIdx.x;
    int v[4]; int s = 0;
    for (int c = 0; c < 4; ++c) {
        int idx = t * 4 + c;
        float d = deg[idx];
        v[c] = (int)(d + 0.5f);
        s += v[c];
        dinv[idx] = rsqrtf(fmaxf(d, 1.0f));
    }
    part[t] = s;
    __syncthreads();
    for (int off = 1; off < 1024; off <<= 1) {
        int add = (t >= off) ? part[t - off] : 0;
        __syncthreads();
        part[t] += add;
        __syncthreads();
    }
    int base = (t == 0) ? 0 : part[t - 1];
    for (int c = 0; c < 4; ++c) {
        int idx = t * 4 + c;
        rowptr[idx] = base;
        cur[idx] = base;
        base += v[c];
    }
    if (t == 1023) rowptr[N_NODES] = base;
}

// ---- Pass 2: extract nonzeros (column-oriented CSR + COO x index), val = dinv[i]*dinv[x]*adj
__global__ void k_fill(const float* __restrict__ adj, const float* __restrict__ dinv,
                       int* __restrict__ cur, int* __restrict__ col_i,
                       int* __restrict__ x_of, float* __restrict__ val) {
    int gx = blockIdx.x * blockDim.x + threadIdx.x;
    int i0 = blockIdx.y * 32;
    const float4* a4 = reinterpret_cast<const float4*>(adj);
    for (int r = 0; r < 32; ++r) {
        int i = i0 + r;
        float4 q = a4[(size_t)i * (N_NODES / 4) + gx];
        float di = dinv[i];
        float qq[4] = {q.x, q.y, q.z, q.w};
        #pragma unroll
        for (int c = 0; c < 4; ++c) {
            if (qq[c] != 0.0f) {
                int x = gx * 4 + c;
                int e = atomicAdd(&cur[x], 1);
                if (e < NNZ_CAP) {
                    col_i[e] = i;
                    x_of[e] = x;
                    val[e] = di * dinv[x] * qq[c];
                }
            }
        }
    }
}

// ---- sW[k][j] = sum_y |W[j, k*128+y]|
__global__ void k_sw(const float* __restrict__ W, float* __restrict__ sW) {
    int tid = blockIdx.x * blockDim.x + threadIdx.x;  // 0..511
    int k = tid >> 7, j = tid & 127;
    float s = 0.f;
    for (int y = 0; y < FEAT; ++y)
        s += fabsf(W[(size_t)j * (KCH * FEAT) + k * FEAT + y]);
    sW[k * FEAT + j] = s;
}

// ---- Row-sum recurrence s_k = 2 L s_{k-1} - s_{k-2}, all in one block via LDS scatter
__global__ __launch_bounds__(1024) void k_schain(const int* __restrict__ rowptr,
                                                 const int* __restrict__ col_i,
                                                 const int* __restrict__ x_of,
                                                 const float* __restrict__ val,
                                                 float* __restrict__ sA) {
    __shared__ float C[N_NODES];   // s1
    __shared__ float Nn[N_NODES];  // s2
    __shared__ float T[N_NODES];   // D*v scratch
    int t = threadIdx.x;
    int nnz = rowptr[N_NODES];
    if (nnz > NNZ_CAP) nnz = NNZ_CAP;
    for (int i = t; i < N_NODES; i += 1024) { T[i] = 0.0f; sA[i] = 1.0f; }
    __syncthreads();
    // s1 = L*1 = 1 - D*1
    for (int e = t; e < nnz; e += 1024) atomicAdd(&T[col_i[e]], val[e]);
    __syncthreads();
    for (int i = t; i < N_NODES; i += 1024) {
        C[i] = 1.0f - T[i];
        sA[N_NODES + i] = C[i];
        T[i] = 0.0f;
    }
    __syncthreads();
    // s2 = 2(C - D*C) - 1
    for (int e = t; e < nnz; e += 1024) atomicAdd(&T[col_i[e]], val[e] * C[x_of[e]]);
    __syncthreads();
    for (int i = t; i < N_NODES; i += 1024) {
        Nn[i] = 2.0f * (C[i] - T[i]) - 1.0f;
        sA[2 * N_NODES + i] = Nn[i];
        T[i] = 0.0f;
    }
    __syncthreads();
    // s3 = 2(Nn - D*Nn) - C
    for (int e = t; e < nnz; e += 1024) atomicAdd(&T[col_i[e]], val[e] * Nn[x_of[e]]);
    __syncthreads();
    for (int i = t; i < N_NODES; i += 1024)
        sA[3 * N_NODES + i] = 2.0f * (Nn[i] - T[i]) - C[i];
}

// ---- c[i,j] = r[i,j] / sum_k sA[k,i]*sW[k,j]
__global__ void k_c(const float* __restrict__ r, const float* __restrict__ sA,
                    const float* __restrict__ sW, float* __restrict__ c) {
    int gid = blockIdx.x * blockDim.x + threadIdx.x;
    int i = gid >> 7, j = gid & 127;
    float denom = 0.f;
    #pragma unroll
    for (int k = 0; k < KCH; ++k) denom += sA[k * N_NODES + i] * sW[k * FEAT + j];
    c[gid] = r[gid] / denom;
}

// ---- M_k[i,y] = sum_j c[i,j] * |W[j, k*128+y]|   (reads W directly, coalesced over y)
__global__ __launch_bounds__(256) void k_m(const float* __restrict__ c,
                                           const float* __restrict__ W,
                                           float* __restrict__ M) {
    __shared__ float cl[32][FEAT];
    int k = blockIdx.y;
    int ib = blockIdx.x * 32;
    int tx = threadIdx.x;
    int y = tx & 127, half = tx >> 7;
    for (int m = tx; m < 32 * FEAT; m += 256)
        cl[m >> 7][m & 127] = c[(size_t)(ib + (m >> 7)) * FEAT + (m & 127)];
    __syncthreads();
    float acc[16];
    #pragma unroll
    for (int u = 0; u < 16; ++u) acc[u] = 0.0f;
    for (int j = 0; j < FEAT; ++j) {
        float a = fabsf(W[(size_t)j * (KCH * FEAT) + k * FEAT + y]);
        #pragma unroll
        for (int u = 0; u < 16; ++u) acc[u] += a * cl[half * 16 + u][j];  // LDS broadcast
    }
    #pragma unroll
    for (int u = 0; u < 16; ++u)
        M[(size_t)k * N_NODES * FEAT + (size_t)(ib + half * 16 + u) * FEAT + y] = acc[u];
}

// ---- out = A - D^T A  (one sparse gather per output row x)
__global__ void k_lap(const int* __restrict__ rowptr, const int* __restrict__ col_i,
                      const float* __restrict__ val, const float* __restrict__ A,
                      float* __restrict__ out) {
    int x = blockIdx.x * 2 + (threadIdx.x >> 7);
    int y = threadIdx.x & 127;
    int e0 = rowptr[x], e1 = rowptr[x + 1];
    if (e1 > NNZ_CAP) e1 = NNZ_CAP;
    float acc = 0.0f;
    for (int e = e0; e < e1; ++e)
        acc += val[e] * A[(size_t)col_i[e] * FEAT + y];
    out[(size_t)x * FEAT + y] = A[(size_t)x * FEAT + y] - acc;
}

// ---- out = M0 + (M1 - D'M1) + (2(U - D'U) - M2) + (4(S - D'S) - 3R)
__global__ void k_final(const int* __restrict__ rowptr, const int* __restrict__ col_i,
                        const float* __restrict__ val, const float* __restrict__ M,
                        const float* __restrict__ U, const float* __restrict__ R,
                        const float* __restrict__ S, float* __restrict__ out) {
    int x = blockIdx.x * 2 + (threadIdx.x >> 7);
    int y = threadIdx.x & 127;
    const float* M0 = M;
    const float* M1 = M + (size_t)N_NODES * FEAT;
    const float* M2 = M + (size_t)2 * N_NODES * FEAT;
    int e0 = rowptr[x], e1 = rowptr[x + 1];
    if (e1 > NNZ_CAP) e1 = NNZ_CAP;
    float g1 = 0.f, g2 = 0.f, g3 = 0.f;
    for (int e = e0; e < e1; ++e) {
        int i = col_i[e];
        float v = val[e];
        size_t o = (size_t)i * FEAT + y;
        g1 += v * M1[o];
        g2 += v * U[o];
        g3 += v * S[o];
    }
    size_t o = (size_t)x * FEAT + y;
    out[o] = M0[o] + (M1[o] - g1) + (2.0f * (U[o] - g2) - M2[o])
           + (4.0f * (S[o] - g3) - 3.0f * R[o]);
}

extern "C" void kernel_launch(void* const* d_in, const int* in_sizes, int n_in,
                              void* d_out, int out_size, void* d_ws, size_t ws_size,
                              hipStream_t stream) {
    const float* r   = (const float*)d_in[1];
    const float* adj = (const float*)d_in[2];
    const float* W   = (const float*)d_in[3];
    float* out = (float*)d_out;

    char* w = (char*)d_ws;
    auto take = [&](size_t bytes) {
        char* p = w;
        w += (bytes + 255) & ~(size_t)255;
        return p;
    };
    float* deg    = (float*)take((size_t)N_NODES * 4);
    float* dinv   = (float*)take((size_t)N_NODES * 4);
    int*   cur    = (int*)take((size_t)N_NODES * 4);
    int*   rowptr = (int*)take((size_t)(N_NODES + 1) * 4);
    int*   col_i  = (int*)take((size_t)NNZ_CAP * 4);
    int*   x_of   = (int*)take((size_t)NNZ_CAP * 4);
    float* val    = (float*)take((size_t)NNZ_CAP * 4);
    float* sW     = (float*)take((size_t)KCH * FEAT * 4);
    float* sA     = (float*)take((size_t)KCH * N_NODES * 4);
    float* c      = (float*)take((size_t)N_NODES * FEAT * 4);
    float* M      = (float*)take((size_t)KCH * N_NODES * FEAT * 4);
    float* U      = (float*)take((size_t)N_NODES * FEAT * 4);
    float* R      = (float*)take((size_t)N_NODES * FEAT * 4);
    float* S      = (float*)take((size_t)N_NODES * FEAT * 4);

    hipMemsetAsync(deg, 0, (size_t)N_NODES * 4, stream);
    k_deg<<<dim3(4, 128), 256, 0, stream>>>(adj, deg);
    k_scan<<<1, 1024, 0, stream>>>(deg, dinv, rowptr, cur);
    k_fill<<<dim3(4, 128), 256, 0, stream>>>(adj, dinv, cur, col_i, x_of, val);
    k_sw<<<2, 256, 0, stream>>>(W, sW);
    k_schain<<<1, 1024, 0, stream>>>(rowptr, col_i, x_of, val, sA);
    k_c<<<(N_NODES * FEAT) / 256, 256, 0, stream>>>(r, sA, sW, c);
    k_m<<<dim3(N_NODES / 32, KCH), 256, 0, stream>>>(c, W, M);
    // U = L^T M2 ; R = L^T M3 ; S = L^T R
    k_lap<<<N_NODES / 2, 256, 0, stream>>>(rowptr, col_i, val,
                                           M + (size_t)2 * N_NODES * FEAT, U);
    k_lap<<<N_NODES / 2, 256, 0, stream>>>(rowptr, col_i, val,
                                           M + (size_t)3 * N_NODES * FEAT, R);
    k_lap<<<N_NODES / 2, 256, 0, stream>>>(rowptr, col_i, val, R, S);
    k_final<<<N_NODES / 2, 256, 0, stream>>>(rowptr, col_i, val, M, U, R, S, out);
}